// Round 4
// baseline (250.404 us; speedup 1.0000x reference)
//
#include <hip/hip_runtime.h>
#include <float.h>

// Sparsemax per row, one WAVE per row — zero __syncthreads in the kernel.
// tau >= max(x)-1 bounds the support (~15-20 of 8192 for Gaussian rows):
// gather those via ballot-compaction, Newton/Michelot on shuffles only.
// Row is re-read from L2 (read ~1us earlier -> resident) instead of LDS,
// so occupancy is wave-limited (32 waves/CU), not LDS-limited.

constexpr int D    = 8192;
constexpr int THREADS = 256;
constexpr int WPB  = THREADS / 64;     // 4 rows per block
constexpr int F4PW = D / (64 * 4);     // 32 f32x4 per lane per row
constexpr int CAP  = 256;              // per-wave candidate capacity

typedef float f32x4 __attribute__((ext_vector_type(4)));

// Wave-wide sum of two values via butterfly; result uniform on all lanes.
__device__ __forceinline__ void wave_reduce2(float& a, float& b) {
    #pragma unroll
    for (int off = 1; off < 64; off <<= 1) {
        a += __shfl_xor(a, off, 64);
        b += __shfl_xor(b, off, 64);
    }
}

__global__ __launch_bounds__(THREADS, 4)
void sparsemax_kernel(const float* __restrict__ x, float* __restrict__ out,
                      int rows) {
    __shared__ float cands[WPB][CAP];

    const int wave = threadIdx.x >> 6;
    const int lane = threadIdx.x & 63;
    const long long row = (long long)blockIdx.x * WPB + wave;
    if (row >= rows) return;
    const f32x4* __restrict__ xr4 = reinterpret_cast<const f32x4*>(x + row * D);
    f32x4* __restrict__       or4 = reinterpret_cast<f32x4*>(out + row * D);

    // ---- scan 1: row max (HBM read, coalesced 1 KiB/wave/inst) ----
    float m = -FLT_MAX;
    #pragma unroll 8
    for (int i = 0; i < F4PW; ++i) {
        f32x4 t = xr4[lane + i * 64];
        m = fmaxf(m, fmaxf(fmaxf(t.x, t.y), fmaxf(t.z, t.w)));
    }
    #pragma unroll
    for (int off = 1; off < 64; off <<= 1)
        m = fmaxf(m, __shfl_xor(m, off, 64));
    const float thr = m - 1.0f;            // tau >= thr always

    // ---- scan 2 (L2-hot): ballot-compact candidates > thr ----
    int n = 0;
    #pragma unroll 8
    for (int i = 0; i < F4PW; ++i) {
        f32x4 t = xr4[lane + i * 64];
        bool any4 = (t.x > thr) | (t.y > thr) | (t.z > thr) | (t.w > thr);
        if (__ballot(any4) == 0ull) continue;   // wave-uniform fast skip
        #pragma unroll
        for (int j = 0; j < 4; ++j) {
            float v = t[j];
            unsigned long long mk = __ballot(v > thr);
            if (v > thr) {
                int pos = n + __popcll(mk & ((1ull << lane) - 1ull));
                if (pos < CAP) cands[wave][pos] = v;
            }
            n += __popcll(mk);
        }
    }

    // ---- Newton/Michelot on candidates, shuffles only ----
    float tau = thr;
    if (n <= CAP) {
        float c0 = (lane           < n) ? cands[wave][lane          ] : -FLT_MAX;
        float c1 = (lane +  64     < n) ? cands[wave][lane +  64    ] : -FLT_MAX;
        float c2 = (lane + 128     < n) ? cands[wave][lane + 128    ] : -FLT_MAX;
        float c3 = (lane + 192     < n) ? cands[wave][lane + 192    ] : -FLT_MAX;
        float kprev = -1.0f;
        for (int it = 0; it < 64; ++it) {     // wave-uniform trip count
            float S = 0.f, K = 0.f;
            if (c0 > tau) { S += c0; K += 1.f; }
            if (c1 > tau) { S += c1; K += 1.f; }
            if (c2 > tau) { S += c2; K += 1.f; }
            if (c3 > tau) { S += c3; K += 1.f; }
            wave_reduce2(S, K);
            tau = (S - 1.f) / K;              // K >= 1: max is in support
            if (K == kprev) break;            // support fixed -> exact tau
            kprev = K;
        }
    } else {
        // Fallback (unreachable for Gaussian input): full-row Michelot, L2 reads.
        float kprev = -1.0f;
        for (int it = 0; it < 64; ++it) {
            float S = 0.f, K = 0.f;
            for (int i = 0; i < F4PW; ++i) {
                f32x4 t = xr4[lane + i * 64];
                #pragma unroll
                for (int j = 0; j < 4; ++j) {
                    float v = t[j];
                    if (v > tau) { S += v; K += 1.f; }
                }
            }
            wave_reduce2(S, K);
            tau = (S - 1.f) / K;
            if (K == kprev) break;
            kprev = K;
        }
    }

    // ---- scan 3 (L2-hot): out = relu(x - tau), nontemporal stores ----
    #pragma unroll 8
    for (int i = 0; i < F4PW; ++i) {
        f32x4 t = xr4[lane + i * 64];
        f32x4 o;
        o.x = fmaxf(t.x - tau, 0.f);
        o.y = fmaxf(t.y - tau, 0.f);
        o.z = fmaxf(t.z - tau, 0.f);
        o.w = fmaxf(t.w - tau, 0.f);
        __builtin_nontemporal_store(o, &or4[lane + i * 64]);
    }
}

extern "C" void kernel_launch(void* const* d_in, const int* in_sizes, int n_in,
                              void* d_out, int out_size, void* d_ws, size_t ws_size,
                              hipStream_t stream) {
    const float* x = (const float*)d_in[0];
    float* out = (float*)d_out;
    const int rows = in_sizes[0] / D;              // 4096
    const int blocks = (rows + WPB - 1) / WPB;     // 1024
    sparsemax_kernel<<<blocks, THREADS, 0, stream>>>(x, out, rows);
}